// Round 16
// baseline (1898.665 us; speedup 1.0000x reference)
//
#include <hip/hip_runtime.h>
#include <math.h>

#define TT 2048
#define HH 64
#define NBLK 64    // 512 elems / 8 per block
#define NTHR 1024  // 16 waves = 2 quads x 8 waves

typedef _Float16 half8 __attribute__((ext_vector_type(8)));
typedef float f32x4 __attribute__((ext_vector_type(4)));

__device__ __forceinline__ float sigmoid_fast(float x) {
    float e = __expf(-x);
    return __builtin_amdgcn_rcpf(1.0f + e);
}
__device__ __forceinline__ float tanh_fast(float x) {
    float e = __expf(-2.0f * x);
    return fmaf(2.0f, __builtin_amdgcn_rcpf(1.0f + e), -1.0f);
}

// Round 16: co-resident independent quads. r15's merged one-barrier step is
// ~1360cy vs an issue floor of ~300-400cy/SIMD at 2 waves/SIMD -> ~70%
// latency stall. Fix (r12's lesson respected: extra waves must do NEW work,
// not redundant reads): 64 blocks x 16 waves = TWO independent 4-elem quads
// per block, each quad = r15's exact 8-wave structure (own glds/hsw; shared
// barrier). 4 waves/SIMD: quad A's chain stalls are filled by quad B's
// issue. Per-gate arithmetic bit-identical to r15 -> absmax 4.882812e-4.
__global__ __launch_bounds__(NTHR) __attribute__((amdgpu_waves_per_eu(4, 4)))
void lstm_quad2_kernel(const float* __restrict__ x,      // [B,T]
                       const float* __restrict__ w_ih0,  // [256,1]
                       const float* __restrict__ w_hh0,  // [256,64]
                       const float* __restrict__ b_ih0,  // [256]
                       const float* __restrict__ b_hh0,  // [256]
                       const float* __restrict__ w_ih1,  // [256,64]
                       const float* __restrict__ w_hh1,  // [256,64]
                       const float* __restrict__ b_ih1,  // [256]
                       const float* __restrict__ b_hh1,  // [256]
                       const float* __restrict__ w1, const float* __restrict__ b1,
                       const float* __restrict__ w2, const float* __restrict__ b2,
                       const float* __restrict__ w3, const float* __restrict__ b3,
                       float* __restrict__ out)          // [B,10]
{
    const int tid = threadIdx.x;
    const int wv  = tid >> 6;        // wave 0..15
    const int l   = tid & 63;
    const int qd  = wv >> 3;         // quad 0/1
    const int sub = wv & 7;          // wave-in-quad
    const int L   = sub >> 2;        // layer this wave owns
    const int j   = sub & 3;         // unit group [16j, 16j+16)
    const int e16 = l & 15;          // MFMA col (elem-in-quad; valid < 4)
    const int kg  = l >> 4;          // k-group / C row-quad
    const int bA  = blockIdx.x * 8;

    __shared__ __align__(16) float xs[8 * (TT + 2)];           // [e][2050]
    __shared__ __align__(16) float glds[2][2][4][4][72];       // [qd][L][g][e][u pad]
    __shared__ __align__(16) _Float16 hsw[2][2][2][16 * 64];   // [qd][L][parity]
    __shared__ float cls1[8][HH];
    __shared__ float cls2[8][32];

    // zero h buffers (rows 4..15 stay zero -> benign B cols)
    for (int i = tid; i < 2 * 2 * 2 * 16 * 64; i += NTHR)
        ((_Float16*)hsw)[i] = (_Float16)0.0f;
    // stage x [e][t] (stride 2050), coalesced reads; pad t=TT with 0
    for (int i = tid; i < 8 * TT; i += NTHR) {
        const int e = i >> 11, t = i & (TT - 1);
        xs[e * (TT + 2) + t] = x[(size_t)(bA + e) * TT + t];
    }
    if (tid < 8) xs[tid * (TT + 2) + TT] = 0.0f;

    // ---- weight A-frags (fp16), uniform 16-slot layout (r15) ----
    half8 wf[16];
    {
        auto frag = [&](const float* M, int g, int kc) {
            const int row = g * 64 + 16 * j + e16;   // A-frag row = l&15
            half8 v;
            #pragma unroll
            for (int i = 0; i < 8; ++i) v[i] = (_Float16)M[row * HH + kc * 32 + kg * 8 + i];
            return v;
        };
        const float* M01 = L ? w_ih1 : w_hh0;
        #pragma unroll
        for (int g = 0; g < 4; ++g) {
            wf[4 * g + 0] = frag(M01, g, 0);
            wf[4 * g + 1] = frag(M01, g, 1);
            if (L) {
                wf[4 * g + 2] = frag(w_hh1, g, 0);
                wf[4 * g + 3] = frag(w_hh1, g, 1);
            } else {
                half8 zz;
                #pragma unroll
                for (int i = 0; i < 8; ++i) zz[i] = (_Float16)0.0f;
                wf[4 * g + 2] = zz;
                wf[4 * g + 3] = zz;
            }
        }
    }

    // ---- act identity: lane owns (L, unit au, elem-in-quad ae) ----
    const int au = 16 * j + (l >> 2);
    const int ae = l & 3;
    float bi[4], wxr[4];
    {
        const float* bihp = L ? b_ih1 : b_ih0;
        const float* bhhp = L ? b_hh1 : b_hh0;
        #pragma unroll
        for (int g = 0; g < 4; ++g) {
            bi[g]  = bihp[g * 64 + au] + bhhp[g * 64 + au];
            wxr[g] = L ? 0.0f : w_ih0[g * 64 + au];
        }
    }
    // pin (rounds 1-4 lesson)
    #pragma unroll
    for (int i = 0; i < 16; ++i) asm volatile("" : "+v"(wf[i]));
    #pragma unroll
    for (int g = 0; g < 4; ++g) {
        asm volatile("" : "+v"(bi[g]));
        asm volatile("" : "+v"(wxr[g]));
    }

    float c = 0.0f;                      // lane's cell state (unit au, elem ae)

    const int swz16 = (e16 & 7) << 4;
    const int hro0 = e16 * 128 + ((16 * kg) ^ swz16);
    const int hro1 = e16 * 128 + ((64 + 16 * kg) ^ swz16);
    const int hwb  = ae * 128 + ((2 * au) ^ (ae << 4));
    const int u0   = 16 * j + 4 * kg;
    const float* xrow = xs + (qd * 4 + ae) * (TT + 2);
    const f32x4 z4 = {0.0f, 0.0f, 0.0f, 0.0f};

    __syncthreads();

    for (int t = 0; t <= TT; ++t) {
        const int rp = t & 1;            // read parity
        // ---- MFMA: raw gates -> glds (wave-own range) ----
        {
            const char* h0r = (const char*)&hsw[qd][0][rp][0];
            const char* h1r = (const char*)&hsw[qd][1][rp][0];
            half8 f0 = *(const half8*)(h0r + hro0);
            half8 f1 = *(const half8*)(h0r + hro1);
            half8 f2 = *(const half8*)(h1r + hro0);
            half8 f3 = *(const half8*)(h1r + hro1);
            f32x4 acc[4];
            #pragma unroll
            for (int g = 0; g < 4; ++g) {
                acc[g] = __builtin_amdgcn_mfma_f32_16x16x32_f16(wf[4 * g + 0], f0, z4, 0, 0, 0);
                acc[g] = __builtin_amdgcn_mfma_f32_16x16x32_f16(wf[4 * g + 1], f1, acc[g], 0, 0, 0);
                acc[g] = __builtin_amdgcn_mfma_f32_16x16x32_f16(wf[4 * g + 2], f2, acc[g], 0, 0, 0);
                acc[g] = __builtin_amdgcn_mfma_f32_16x16x32_f16(wf[4 * g + 3], f3, acc[g], 0, 0, 0);
            }
            if (e16 < 4) {
                #pragma unroll
                for (int g = 0; g < 4; ++g)
                    *(f32x4*)&glds[qd][L][g][e16][u0] = acc[g];
            }
        }
        // ---- same-wave readback + act (1 unit-elem/lane) ----
        {
            float z0 = glds[qd][L][0][ae][au];
            float z1 = glds[qd][L][1][ae][au];
            float z2 = glds[qd][L][2][ae][au];
            float z3 = glds[qd][L][3][ae][au];
            const float xt = xrow[t];
            z0 += fmaf(wxr[0], xt, bi[0]);
            z1 += fmaf(wxr[1], xt, bi[1]);
            z2 += fmaf(wxr[2], xt, bi[2]);
            z3 += fmaf(wxr[3], xt, bi[3]);
            float gi = sigmoid_fast(z0);
            float gf = sigmoid_fast(z1);
            float gg = tanh_fast(z2);
            float go = sigmoid_fast(z3);
            c = fmaf(gf, c, gi * gg);
            float h = go * tanh_fast(c);
            if (L && t == 0) { c = 0.0f; h = 0.0f; }   // enforce h1(-1)=0
            *(_Float16*)((char*)&hsw[qd][L][rp ^ 1][0] + hwb) = (_Float16)h;
        }
        __syncthreads();
    }
    // h_last = h1(TT-1), parity 1, per quad

    // ---- classifier head: wave wv<8 handles elem wv ----
    if (wv < 8) {
        const int q = wv >> 2, col = wv & 3;
        const char* h1f = (const char*)&hsw[q][1][1][0];
        float a = b1[l];
        #pragma unroll 8
        for (int k = 0; k < HH; ++k) {
            const float hk = (float)*(const _Float16*)(h1f + col * 128 + ((2 * k) ^ (col << 4)));
            a = fmaf(w1[l * HH + k], hk, a);
        }
        cls1[wv][l] = fmaxf(a, 0.0f);
    }
    __syncthreads();
    if (wv < 8 && l < 32) {
        float a = b2[l];
        #pragma unroll 8
        for (int k = 0; k < HH; ++k) a = fmaf(w2[l * HH + k], cls1[wv][k], a);
        cls2[wv][l] = fmaxf(a, 0.0f);
    }
    __syncthreads();
    if (wv < 8 && l < 10) {
        float a = b3[l];
        #pragma unroll
        for (int k = 0; k < 32; ++k) a = fmaf(w3[l * 32 + k], cls2[wv][k], a);
        out[(size_t)(bA + wv) * 10 + l] = a;
    }
}

extern "C" void kernel_launch(void* const* d_in, const int* in_sizes, int n_in,
                              void* d_out, int out_size, void* d_ws, size_t ws_size,
                              hipStream_t stream) {
    const float* x     = (const float*)d_in[0];
    const float* w_ih0 = (const float*)d_in[1];
    const float* w_hh0 = (const float*)d_in[2];
    const float* b_ih0 = (const float*)d_in[3];
    const float* b_hh0 = (const float*)d_in[4];
    const float* w_ih1 = (const float*)d_in[5];
    const float* w_hh1 = (const float*)d_in[6];
    const float* b_ih1 = (const float*)d_in[7];
    const float* b_hh1 = (const float*)d_in[8];
    const float* w1    = (const float*)d_in[9];
    const float* b1    = (const float*)d_in[10];
    const float* w2    = (const float*)d_in[11];
    const float* b2    = (const float*)d_in[12];
    const float* w3    = (const float*)d_in[13];
    const float* b3    = (const float*)d_in[14];
    float* out = (float*)d_out;

    lstm_quad2_kernel<<<NBLK, NTHR, 0, stream>>>(x, w_ih0, w_hh0, b_ih0, b_hh0,
                                                 w_ih1, w_hh1, b_ih1, b_hh1,
                                                 w1, b1, w2, b2, w3, b3, out);
}

// Round 17
// 1121.761 us; speedup vs baseline: 1.6926x; 1.6926x over previous
//
#include <hip/hip_runtime.h>
#include <math.h>

#define TT 2048
#define HH 64
#define NE 4       // batch elems per block
#define NBLK 128   // 512 / NE
#define NTHR 512   // 8 waves: (L = wv>>2, j = wv&3)

typedef _Float16 half8 __attribute__((ext_vector_type(8)));
typedef float f32x4 __attribute__((ext_vector_type(4)));

__device__ __forceinline__ float sigmoid_fast(float x) {
    float e = __expf(-x);
    return __builtin_amdgcn_rcpf(1.0f + e);
}
__device__ __forceinline__ float tanh_fast(float x) {
    float e = __expf(-2.0f * x);
    return fmaf(2.0f, __builtin_amdgcn_rcpf(1.0f + e), -1.0f);
}

// Round 17: r15 structure (one barrier/step, merged MFMA+act, 1248->1159us)
// with two surgical cuts, motivated by r12/r16 diagnosis that the step is
// ISSUE + LDS-BANDWIDTH bound (step scaled with waves, not with chain):
//  1. Broadcast-aliased B-frag reads: lanes e16>=4 alias their frag address
//     to col 0 (same-address lanes broadcast for free) -> frag LDS traffic
//     per wave-op 1KB -> 256B (cols 4-15 were garbage anyway; C cols 4-15
//     are duplicates of col 0, never stored).
//  2. L0 waves read only h0 frags and issue only the 8 real MFMAs (r15's
//     8 zero-weight MFMAs added exact +0 -> removal is bit-identical).
// Frag LDS: 32KB -> 6KB/step (~-260 cyc at 128B/cyc); -70 cyc SIMD issue.
// Everything else (parities, act mapping, swizzles, head) byte-identical to
// r15 -> absmax must stay 4.882812e-4.
__global__ __launch_bounds__(NTHR) __attribute__((amdgpu_waves_per_eu(4, 4)))
void lstm_merged_kernel(const float* __restrict__ x,      // [B,T]
                        const float* __restrict__ w_ih0,  // [256,1]
                        const float* __restrict__ w_hh0,  // [256,64]
                        const float* __restrict__ b_ih0,  // [256]
                        const float* __restrict__ b_hh0,  // [256]
                        const float* __restrict__ w_ih1,  // [256,64]
                        const float* __restrict__ w_hh1,  // [256,64]
                        const float* __restrict__ b_ih1,  // [256]
                        const float* __restrict__ b_hh1,  // [256]
                        const float* __restrict__ w1, const float* __restrict__ b1,
                        const float* __restrict__ w2, const float* __restrict__ b2,
                        const float* __restrict__ w3, const float* __restrict__ b3,
                        float* __restrict__ out)          // [B,10]
{
    const int tid = threadIdx.x;
    const int wv  = tid >> 6;        // wave 0..7
    const int l   = tid & 63;
    const int L   = wv >> 2;         // layer this wave owns
    const int j   = wv & 3;          // unit group [16j, 16j+16)
    const int e16 = l & 15;          // MFMA col (elem; valid < NE)
    const int kg  = l >> 4;          // k-group / C row-quad
    const int bA  = blockIdx.x * NE;

    __shared__ __align__(16) float xs[(TT + 1) * (NE + 1)];    // [t][5] pad
    __shared__ __align__(16) float glds[2][4][NE][72];         // [L][g][e][u pad]
    __shared__ __align__(16) _Float16 hsw[2][2][16 * 64];      // [L][parity] swizzled
    __shared__ float cls1[NE][HH];
    __shared__ float cls2[NE][32];

    // zero h buffers (rows 4..15 stay zero -> benign B cols)
    for (int i = tid; i < 2 * 2 * 16 * 64; i += NTHR)
        ((_Float16*)hsw)[i] = (_Float16)0.0f;
    // stage x: xs[t*5+e] (stride-5 conflict-free), coalesced reads; pad t=TT
    for (int i = tid; i < NE * TT; i += NTHR) {
        const int e = i >> 11, t = i & (TT - 1);
        xs[t * (NE + 1) + e] = x[(size_t)(bA + e) * TT + t];
    }
    if (tid < NE + 1) xs[TT * (NE + 1) + tid] = 0.0f;

    // ---- weight A-frags (fp16), uniform 16-slot layout (r15) ----
    // wf[4g+0,1] = (L ? Wih1 : Whh0)(g,j) kc=0,1
    // wf[4g+2,3] = L ? Whh1(g,j) kc=0,1 : ZERO (unused by L0 exec path)
    half8 wf[16];
    {
        auto frag = [&](const float* M, int g, int kc) {
            const int row = g * 64 + 16 * j + e16;   // A-frag row = l&15
            half8 v;
            #pragma unroll
            for (int i = 0; i < 8; ++i) v[i] = (_Float16)M[row * HH + kc * 32 + kg * 8 + i];
            return v;
        };
        const float* M01 = L ? w_ih1 : w_hh0;
        #pragma unroll
        for (int g = 0; g < 4; ++g) {
            wf[4 * g + 0] = frag(M01, g, 0);
            wf[4 * g + 1] = frag(M01, g, 1);
            if (L) {
                wf[4 * g + 2] = frag(w_hh1, g, 0);
                wf[4 * g + 3] = frag(w_hh1, g, 1);
            } else {
                half8 zz;
                #pragma unroll
                for (int i = 0; i < 8; ++i) zz[i] = (_Float16)0.0f;
                wf[4 * g + 2] = zz;
                wf[4 * g + 3] = zz;
            }
        }
    }

    // ---- act identity: lane owns (L, unit au, elem ae) ----
    const int au = 16 * j + (l >> 2);    // unit, within wave's own group
    const int ae = l & 3;                // elem
    float bi[4], wxr[4];
    {
        const float* bihp = L ? b_ih1 : b_ih0;
        const float* bhhp = L ? b_hh1 : b_hh0;
        #pragma unroll
        for (int g = 0; g < 4; ++g) {
            bi[g]  = bihp[g * 64 + au] + bhhp[g * 64 + au];
            wxr[g] = L ? 0.0f : w_ih0[g * 64 + au];
        }
    }
    // pin (rounds 1-4 lesson: allocator rematerializes weight loads otherwise)
    #pragma unroll
    for (int i = 0; i < 16; ++i) asm volatile("" : "+v"(wf[i]));
    #pragma unroll
    for (int g = 0; g < 4; ++g) {
        asm volatile("" : "+v"(bi[g]));
        asm volatile("" : "+v"(wxr[g]));
    }

    float c = 0.0f;                      // lane's cell state (unit au, elem ae)

    // Broadcast-aliased frag addresses: cols >=4 read col 0 (same-address
    // broadcast, free) -> 256B instead of 1KB moved per wave-op.
    const int e4   = (e16 < NE) ? e16 : 0;
    const int swz4 = (e4 & 7) << 4;
    const int hro0 = e4 * 128 + ((16 * kg) ^ swz4);          // k-chunk 0
    const int hro1 = e4 * 128 + ((64 + 16 * kg) ^ swz4);     // k-chunk 1
    const int hwb  = ae * 128 + ((2 * au) ^ (ae << 4));      // act h write byte
    const int u0   = 16 * j + 4 * kg;
    const f32x4 z4 = {0.0f, 0.0f, 0.0f, 0.0f};

    __syncthreads();

    for (int t = 0; t <= TT; ++t) {
        const int rp = t & 1;            // read parity
        // ---- MFMA: gates(L==0: gates0(t); L==1: gates1(t-1)), raw, no bias ----
        {
            f32x4 acc[4];
            if (L) {
                const char* h0r = (const char*)&hsw[0][rp][0];
                const char* h1r = (const char*)&hsw[1][rp][0];
                half8 f0 = *(const half8*)(h0r + hro0);
                half8 f1 = *(const half8*)(h0r + hro1);
                half8 f2 = *(const half8*)(h1r + hro0);
                half8 f3 = *(const half8*)(h1r + hro1);
                #pragma unroll
                for (int g = 0; g < 4; ++g) {
                    acc[g] = __builtin_amdgcn_mfma_f32_16x16x32_f16(wf[4 * g + 0], f0, z4, 0, 0, 0);
                    acc[g] = __builtin_amdgcn_mfma_f32_16x16x32_f16(wf[4 * g + 1], f1, acc[g], 0, 0, 0);
                    acc[g] = __builtin_amdgcn_mfma_f32_16x16x32_f16(wf[4 * g + 2], f2, acc[g], 0, 0, 0);
                    acc[g] = __builtin_amdgcn_mfma_f32_16x16x32_f16(wf[4 * g + 3], f3, acc[g], 0, 0, 0);
                }
            } else {
                const char* h0r = (const char*)&hsw[0][rp][0];
                half8 f0 = *(const half8*)(h0r + hro0);
                half8 f1 = *(const half8*)(h0r + hro1);
                #pragma unroll
                for (int g = 0; g < 4; ++g) {
                    acc[g] = __builtin_amdgcn_mfma_f32_16x16x32_f16(wf[4 * g + 0], f0, z4, 0, 0, 0);
                    acc[g] = __builtin_amdgcn_mfma_f32_16x16x32_f16(wf[4 * g + 1], f1, acc[g], 0, 0, 0);
                }
            }
            if (e16 < NE) {
                #pragma unroll
                for (int g = 0; g < 4; ++g)
                    *(f32x4*)&glds[L][g][e16][u0] = acc[g];
            }
        }
        // ---- same-wave readback + act (1 unit-elem/lane, 10 trans) ----
        {
            float z0 = glds[L][0][ae][au];
            float z1 = glds[L][1][ae][au];
            float z2 = glds[L][2][ae][au];
            float z3 = glds[L][3][ae][au];
            const float xt = xs[t * (NE + 1) + ae];
            z0 += fmaf(wxr[0], xt, bi[0]);
            z1 += fmaf(wxr[1], xt, bi[1]);
            z2 += fmaf(wxr[2], xt, bi[2]);
            z3 += fmaf(wxr[3], xt, bi[3]);
            float gi = sigmoid_fast(z0);
            float gf = sigmoid_fast(z1);
            float gg = tanh_fast(z2);
            float go = sigmoid_fast(z3);
            c = fmaf(gf, c, gi * gg);
            float h = go * tanh_fast(c);
            if (L && t == 0) { c = 0.0f; h = 0.0f; }   // enforce h1(-1)=0
            *(_Float16*)((char*)&hsw[L][rp ^ 1][0] + hwb) = (_Float16)h;
        }
        __syncthreads();
    }
    // h_last = h1(TT-1), written at t=TT into parity (TT&1)^1 = 1

    // ---- classifier head: wave wv<4 handles elem wv ----
    if (wv < 4) {
        const char* h1f = (const char*)&hsw[1][1][0];
        float a = b1[l];
        #pragma unroll 8
        for (int k = 0; k < HH; ++k) {
            const float hk = (float)*(const _Float16*)(h1f + wv * 128 + ((2 * k) ^ (wv << 4)));
            a = fmaf(w1[l * HH + k], hk, a);
        }
        cls1[wv][l] = fmaxf(a, 0.0f);
    }
    __syncthreads();
    if (wv < 4 && l < 32) {
        float a = b2[l];
        #pragma unroll 8
        for (int k = 0; k < HH; ++k) a = fmaf(w2[l * HH + k], cls1[wv][k], a);
        cls2[wv][l] = fmaxf(a, 0.0f);
    }
    __syncthreads();
    if (wv < 4 && l < 10) {
        float a = b3[l];
        #pragma unroll
        for (int k = 0; k < 32; ++k) a = fmaf(w3[l * 32 + k], cls2[wv][k], a);
        out[(size_t)(bA + wv) * 10 + l] = a;
    }
}

extern "C" void kernel_launch(void* const* d_in, const int* in_sizes, int n_in,
                              void* d_out, int out_size, void* d_ws, size_t ws_size,
                              hipStream_t stream) {
    const float* x     = (const float*)d_in[0];
    const float* w_ih0 = (const float*)d_in[1];
    const float* w_hh0 = (const float*)d_in[2];
    const float* b_ih0 = (const float*)d_in[3];
    const float* b_hh0 = (const float*)d_in[4];
    const float* w_ih1 = (const float*)d_in[5];
    const float* w_hh1 = (const float*)d_in[6];
    const float* b_ih1 = (const float*)d_in[7];
    const float* b_hh1 = (const float*)d_in[8];
    const float* w1    = (const float*)d_in[9];
    const float* b1    = (const float*)d_in[10];
    const float* w2    = (const float*)d_in[11];
    const float* b2    = (const float*)d_in[12];
    const float* w3    = (const float*)d_in[13];
    const float* b3    = (const float*)d_in[14];
    float* out = (float*)d_out;

    lstm_merged_kernel<<<NBLK, NTHR, 0, stream>>>(x, w_ih0, w_hh0, b_ih0, b_hh0,
                                                  w_ih1, w_hh1, b_ih1, b_hh1,
                                                  w1, b1, w2, b2, w3, b3, out);
}